// Round 4
// baseline (126.966 us; speedup 1.0000x reference)
//
#include <hip/hip_runtime.h>
#include <hip/hip_fp16.h>

// Problem constants (from the reference).
constexpr int S  = 51;   // seq positions
constexpr int V  = 64;   // vocab
constexpr int E  = 4;    // embedding dim
constexpr int H1 = 5;
constexpr int H2 = 7;
constexpr int D  = 64;   // output dim

constexpr int ROWS  = 256;   // batch rows per gather block (1 block per CU)
constexpr int MAXSC = 13;    // max s-chunk staged in LDS (13,13,13,12)

// ---------------------------------------------------------------------------
// Kernel 1: build fp16 table Y[s][v][d] = tanh(W3[s] @ h2(s,v) + b3[s]).
// Whole MLP depends only on (s, token): 3264 rows x 64 d, 408 KB fp16.
// ---------------------------------------------------------------------------
__global__ void build_table_kernel(const float* __restrict__ emb,
                                   const float* __restrict__ W1,
                                   const float* __restrict__ b1,
                                   const float* __restrict__ W2,
                                   const float* __restrict__ b2,
                                   const float* __restrict__ W3,
                                   const float* __restrict__ b3,
                                   __half* __restrict__ Y) {
  const int sv = blockIdx.x;     // sv = s*64 + v
  const int s  = sv >> 6;
  const int d  = threadIdx.x;    // 0..63

  float e[E];
#pragma unroll
  for (int i = 0; i < E; ++i) e[i] = emb[sv * E + i];

  float h1[H1];
#pragma unroll
  for (int h = 0; h < H1; ++h) {
    float a = b1[s * H1 + h];
#pragma unroll
    for (int i = 0; i < E; ++i) a = fmaf(W1[(s * H1 + h) * E + i], e[i], a);
    h1[h] = (a >= 0.f) ? a : 0.01f * a;   // leaky_relu
  }

  float h2[H2];
#pragma unroll
  for (int g = 0; g < H2; ++g) {
    float a = b2[s * H2 + g];
#pragma unroll
    for (int h = 0; h < H1; ++h) a = fmaf(W2[(s * H2 + g) * H1 + h], h1[h], a);
    h2[g] = (a >= 0.f) ? a : 0.01f * a;
  }

  float a = b3[s * D + d];
#pragma unroll
  for (int g = 0; g < H2; ++g) a = fmaf(W3[(s * D + d) * H2 + g], h2[g], a);

  Y[sv * D + d] = __float2half(tanhf(a));
}

// ---------------------------------------------------------------------------
// Kernel 2: out[b][d] = sum_s Y[s, x[b,s], d]  -- LDS-staged gather.
// Grid = 256 blocks (one per CU), 256 rows each. Tokens (pre-shifted to
// row-byte offsets t<<7) and the table (4 s-chunks of <=13 s, 104 KB) live
// in LDS; inner step per (row,s): ds_read_b32 token (8-lane broadcast,
// conflict-free) + ds_read_b128 table slice (each 8-lane row-octet covers
// all 32 banks exactly once -> even distribution, no hot bank) + 4 pk_add.
// fp16 partials promoted to fp32 every <=4 s (error well under the 0.0625
// floor already present).
// ---------------------------------------------------------------------------
__global__ __launch_bounds__(256, 1) void gather_sum_kernel(
    const int* __restrict__ x, const __half* __restrict__ Y,
    float* __restrict__ out) {
  __shared__ __align__(16) __half tab[MAXSC * V * D];   // 106,496 B
  __shared__ __align__(16) int    tok[ROWS * S];        //  52,224 B  (total 158.7 KB)

  const int tid     = threadIdx.x;
  const int rowbase = blockIdx.x * ROWS;

  // Stage tokens, pre-shifted to table-row byte offsets (t * 128).
  for (int i = tid; i < ROWS * S; i += 256) tok[i] = x[rowbase * S + i] << 7;

  const int li   = tid & 7;          // d-octet 0..7
  const int rix  = (tid >> 3) & 31;  // row-in-group 0..31
  const int li16 = li << 4;          // byte offset of this lane's 16B slice

  float acc[8][8];
#pragma unroll
  for (int a = 0; a < 8; ++a)
#pragma unroll
    for (int b = 0; b < 8; ++b) acc[a][b] = 0.f;

  __half2 a16[8][4];
#pragma unroll
  for (int a = 0; a < 8; ++a)
#pragma unroll
    for (int k = 0; k < 4; ++k) a16[a][k] = __half2(__float2half(0.f), __float2half(0.f));

  const char* tabb = (const char*)tab;

  for (int c = 0; c < 4; ++c) {
    const int s0 = c * 13;
    const int sc = (c < 3) ? 13 : 12;

    __syncthreads();   // prior chunk fully consumed (also covers token staging)
    {
      // Stage table chunk: sc*64 rows x 128 B, fully coalesced.
      const uint4* src = (const uint4*)(Y + s0 * (V * D));
      uint4*       dst = (uint4*)tab;
      const int n4 = sc * (V * D / 8);           // 6656 or 6144 uint4s
      for (int i = tid; i < n4; i += 256) dst[i] = src[i];
    }
    __syncthreads();

    for (int sl = 0; sl < sc; ++sl) {
      const int tokoff = rix * S + s0 + sl;      // + ri*32*S as imm offset below
      const int slbase = sl * (V * D * 2) + li16;
#pragma unroll
      for (int ri = 0; ri < 8; ++ri) {
        const int taddr = tok[ri * 32 * S + tokoff];             // t<<7
        const uint4 v = *(const uint4*)(tabb + (slbase + taddr));
        union { uint4 u; __half2 h[4]; } cv; cv.u = v;
#pragma unroll
        for (int k = 0; k < 4; ++k) a16[ri][k] = __hadd2(a16[ri][k], cv.h[k]);
      }
      // Promote packed-fp16 partials to fp32 every 4 s (and at chunk end).
      if ((sl & 3) == 3 || sl == sc - 1) {
#pragma unroll
        for (int ri = 0; ri < 8; ++ri)
#pragma unroll
          for (int k = 0; k < 4; ++k) {
            const float2 f = __half22float2(a16[ri][k]);
            acc[ri][2 * k]     += f.x;
            acc[ri][2 * k + 1] += f.y;
            a16[ri][k] = __half2(__float2half(0.f), __float2half(0.f));
          }
      }
    }
  }

  // Epilogue: each wave writes 8 rows x 256 B contiguous per ri.
#pragma unroll
  for (int ri = 0; ri < 8; ++ri) {
    const int row = rowbase + ri * 32 + rix;
    float4* o = (float4*)(out + row * D + li * 8);
    o[0] = make_float4(acc[ri][0], acc[ri][1], acc[ri][2], acc[ri][3]);
    o[1] = make_float4(acc[ri][4], acc[ri][5], acc[ri][6], acc[ri][7]);
  }
}

// ---------------------------------------------------------------------------
extern "C" void kernel_launch(void* const* d_in, const int* in_sizes, int n_in,
                              void* d_out, int out_size, void* d_ws, size_t ws_size,
                              hipStream_t stream) {
  const int*   x   = (const int*)d_in[0];
  const float* emb = (const float*)d_in[1];
  const float* W1  = (const float*)d_in[2];
  const float* b1  = (const float*)d_in[3];
  const float* W2  = (const float*)d_in[4];
  const float* b2  = (const float*)d_in[5];
  const float* W3  = (const float*)d_in[6];
  const float* b3  = (const float*)d_in[7];

  const int B = in_sizes[0] / S;          // 65536
  __half* Y = (__half*)d_ws;              // S*V*D halves = 417,792 bytes

  build_table_kernel<<<S * V, D, 0, stream>>>(emb, W1, b1, W2, b2, W3, b3, Y);

  // One block per CU, 256 rows each.
  gather_sum_kernel<<<B / ROWS, 256, 0, stream>>>(x, Y, (float*)d_out);
}